// Round 4
// baseline (382.942 us; speedup 1.0000x reference)
//
#include <hip/hip_runtime.h>
#include <hip/hip_bf16.h>

typedef __attribute__((ext_vector_type(8))) short bf16x8;
typedef __attribute__((ext_vector_type(4))) float f32x4;

#define B_N   4
#define C_IN  32
#define C_OUT 64
#define S_H   32
#define S_W   64
#define S_D   64
#define HWD   (S_H * S_W * S_D)   /* 131072 */

// ws layout: [Wpk 4*28*64*8 ushorts][Zpf 16 floats]
#define WPK_USHORTS     (4 * 28 * 64 * 8)              /* 57344 */
#define WS_NEEDED       ((size_t)WPK_USHORTS * 2 + 64)

__device__ __forceinline__ ushort f2bf(float f) {
    unsigned u = __builtin_bit_cast(unsigned, f);
    unsigned r = (u + 0x7FFFu + ((u >> 16) & 1u)) >> 16;  // RNE
    return (ushort)r;
}

typedef const __attribute__((address_space(1))) unsigned int* dma_gptr;
typedef __attribute__((address_space(3))) unsigned int* dma_lptr;

__device__ __forceinline__ void dma16(const void* g, void* l) {
    __builtin_amdgcn_global_load_lds((dma_gptr)g, (dma_lptr)l, 16, 0, 0);
}

// pinned async global load: issued exactly here, untracked by the legalizer;
// consumer MUST execute an explicit s_waitcnt vmcnt before reading dst.
__device__ __forceinline__ void pin_load(float& dst, const float* p) {
    asm volatile("global_load_dword %0, %1, off" : "=v"(dst) : "v"(p));
}

// ---- prep: pack weights [cic][tap28][co64][ci8] bf16; also zero-page -----
__global__ __launch_bounds__(256) void pack_w_kernel(
    const float* __restrict__ Wt, ushort* __restrict__ Wpk, float* __restrict__ Zpf)
{
    int idx = blockIdx.x * 256 + threadIdx.x;       // 4*28*64 = 7168
    int cic = idx / 1792;
    int r   = idx - cic * 1792;
    int tap = r >> 6;
    int co  = r & 63;
    bf16x8 pk;
    #pragma unroll
    for (int j = 0; j < 8; ++j)
        pk[j] = (tap < 27) ? (short)f2bf(Wt[((long)co * C_IN + cic * 8 + j) * 27 + tap])
                           : (short)0;
    *((bf16x8*)Wpk + idx) = pk;
    if (blockIdx.x == 0 && threadIdx.x < 16) Zpf[threadIdx.x] = 0.f;
}

// ---- main: implicit-GEMM conv3d, fused fp32->bf16 X staging --------------
// Block tile 64co x 256n (4w x 64d). Each wave: 64co x 64n, 4x4 tiles of
// 16x16x32 MFMA. W staged via global_load_lds (L2-resident Wpk).
// X prefetch for cic+1 issued via PINNED asm global_load_dword BEFORE the
// MFMA section (R2's compiler sank tracked loads to the use site: VGPR=84
// proved xv was not live across compute -> ~600cy latency serialized per
// cic -> all pipes ~25%). Drain discipline (rule #18, vmem flavor):
// explicit s_waitcnt vmcnt(0) + sched_barrier(0) after the post-compute
// barrier, BEFORE W-DMA issue and cvt -- never rely on the barrier's
// implicit waits for untracked asm loads. vmcnt decrements in issue order,
// so the prologue's vmcnt(7) (40 X + 7 W outstanding) drains all X loads.
__global__ __launch_bounds__(256, 3) void conv3d_fused_kernel(
    const float* __restrict__ X, const ushort* __restrict__ Wpk,
    const float* __restrict__ Zpf,
    const float* __restrict__ bias, float* __restrict__ out)
{
    __shared__ ushort Xs[1188 * 8];      // [hh3][ww6][dpos66][ci8]  19008 B
    __shared__ ushort Ws[1792 * 8];      // [tap28][co64][ci8]       28672 B

    const int tid  = threadIdx.x;
    const int lane = tid & 63;
    const int wave = tid >> 6;
    const int nl   = lane & 15;
    const int quad = lane >> 4;

    const int blk = blockIdx.x;       // 2048 blocks = (b4, h32, wt16)
    const int wt  = blk & 15;
    const int h   = (blk >> 4) & 31;
    const int b   = blk >> 9;
    const int w0  = wt * 4;

    // ---- per-site X pointers; pad sites -> zero page with stride 0 --------
    const float* xb[5];
    int adv[5];
    #pragma unroll
    for (int k = 0; k < 5; ++k) {
        int s = tid + k * 256;
        xb[k] = Zpf; adv[k] = 0;
        if (s < 1188) {
            int hh   = s / 396;           // 6*66
            int r0   = s - hh * 396;
            int ww   = r0 / 66;
            int dpos = r0 - ww * 66;
            int hp  = h - 1 + hh;
            int wp2 = w0 - 1 + ww;
            int dp  = dpos - 1;
            bool ok = (unsigned)hp < S_H && (unsigned)wp2 < S_W && (unsigned)dp < S_D;
            if (ok) {
                xb[k]  = X + ((((long)b * C_IN) * S_H + hp) * S_W + wp2) * S_D + dp;
                adv[k] = HWD;
            }
        }
    }

    // ---- per-tg LDS offsets (ushort units) --------------------------------
    int a_off[7], b_off[7];
    #pragma unroll
    for (int tg = 0; tg < 7; ++tg) {
        int tap = tg * 4 + quad;
        int tb  = tap < 27 ? tap : 0;      // pad tap: A rows are zero anyway
        int kh = tb / 9;
        int r9 = tb - kh * 9;
        int kw = r9 / 3;
        int kd = r9 - kw * 3;
        a_off[tg] = (tap * 64 + nl) * 8;
        b_off[tg] = (((kh * 6 + kw + wave) * 66) + kd + nl) * 8;  // ww = wave+kw
    }

    float bs[16];
    #pragma unroll
    for (int mi = 0; mi < 4; ++mi)
        #pragma unroll
        for (int r = 0; r < 4; ++r)
            bs[mi * 4 + r] = bias[mi * 16 + quad * 4 + r];

    f32x4 acc[16];
    #pragma unroll
    for (int i = 0; i < 16; ++i) acc[i] = (f32x4){0.f, 0.f, 0.f, 0.f};

    float xv[5][8];

    // ---- prologue: pinned X loads chunk 0 + W chunk 0 DMA -----------------
    #pragma unroll
    for (int k = 0; k < 5; ++k) {
        int s = tid + k * 256;
        if (s < 1188) {
            #pragma unroll
            for (int j = 0; j < 8; ++j)
                pin_load(xv[k][j], xb[k] + (long)j * adv[k]);
        }
    }
    __builtin_amdgcn_sched_barrier(0);
    #pragma unroll
    for (int k = 0; k < 7; ++k) {
        int s = tid + k * 256;
        dma16(Wpk + s * 8, &Ws[s * 8]);
    }
    __builtin_amdgcn_sched_barrier(0);
    asm volatile("s_waitcnt vmcnt(7)" ::: "memory");   // X drained, W in flight
    __builtin_amdgcn_sched_barrier(0);
    #pragma unroll
    for (int k = 0; k < 5; ++k) {
        int s = tid + k * 256;
        if (s < 1188) {
            bf16x8 pk;
            #pragma unroll
            for (int j = 0; j < 8; ++j) pk[j] = (short)f2bf(xv[k][j]);
            *(bf16x8*)&Xs[s * 8] = pk;
        }
    }

    for (int cic = 0; cic < 4; ++cic) {
        __syncthreads();                 // drains W DMA; Xs[cic] visible

        // pinned async X loads for chunk cic+1 (issued BEFORE compute)
        if (cic < 3) {
            #pragma unroll
            for (int k = 0; k < 5; ++k) {
                int s = tid + k * 256;
                if (s < 1188) {
                    #pragma unroll
                    for (int j = 0; j < 8; ++j)
                        pin_load(xv[k][j],
                                 xb[k] + (long)((cic + 1) * 8 + j) * adv[k]);
                }
            }
        }
        __builtin_amdgcn_sched_barrier(0);   // loads stay above compute

        #pragma unroll
        for (int tg = 0; tg < 7; ++tg) {
            bf16x8 af[4], bf[4];
            #pragma unroll
            for (int mi = 0; mi < 4; ++mi)
                af[mi] = *(const bf16x8*)&Ws[a_off[tg] + mi * 128];   // +mi*16 co
            #pragma unroll
            for (int dt = 0; dt < 4; ++dt)
                bf[dt] = *(const bf16x8*)&Xs[b_off[tg] + dt * 128];   // +dt*16 d
            #pragma unroll
            for (int mi = 0; mi < 4; ++mi)
                #pragma unroll
                for (int dt = 0; dt < 4; ++dt)
                    acc[mi * 4 + dt] = __builtin_amdgcn_mfma_f32_16x16x32_bf16(
                        af[mi], bf[dt], acc[mi * 4 + dt], 0, 0, 0);
        }

        if (cic < 3) {
            __syncthreads();             // compute done; safe to overwrite LDS
            // explicit drain of the pinned X loads (do NOT rely on barrier's
            // implicit waits -- asm loads are untracked). They had the whole
            // MFMA section to complete, so this is ~free.
            asm volatile("s_waitcnt vmcnt(0)" ::: "memory");
            __builtin_amdgcn_sched_barrier(0);

            // W chunk cic+1 DMA (drains at next top barrier, behind cvt)
            {
                const ushort* src = Wpk + (long)(cic + 1) * 1792 * 8;
                #pragma unroll
                for (int k = 0; k < 7; ++k) {
                    int s = tid + k * 256;
                    dma16(src + s * 8, &Ws[s * 8]);
                }
            }
            // cvt + write chunk cic+1 (X data already in regs, no wait)
            #pragma unroll
            for (int k = 0; k < 5; ++k) {
                int s = tid + k * 256;
                if (s < 1188) {
                    bf16x8 pk;
                    #pragma unroll
                    for (int j = 0; j < 8; ++j) pk[j] = (short)f2bf(xv[k][j]);
                    *(bf16x8*)&Xs[s * 8] = pk;
                }
            }
        }
    }

    // ---- epilogue: co = mi*16 + quad*4 + r, n = (w0+wave, dt*16+nl) -------
    const int w = w0 + wave;
    #pragma unroll
    for (int mi = 0; mi < 4; ++mi) {
        #pragma unroll
        for (int dt = 0; dt < 4; ++dt) {
            f32x4 a = acc[mi * 4 + dt];
            int d0 = dt * 16 + nl;
            #pragma unroll
            for (int r = 0; r < 4; ++r) {
                int co = mi * 16 + quad * 4 + r;
                out[(((long)(b * C_OUT + co) * S_H + h) * S_W + w) * S_D + d0]
                    = a[r] + bs[mi * 4 + r];
            }
        }
    }
}

// ---- fallback (no workspace needed) ---------------------------------------
__global__ __launch_bounds__(256) void conv3d_mfma_fallback(
    const float* __restrict__ X, const float* __restrict__ Wt,
    const float* __restrict__ bias, float* __restrict__ out)
{
    __shared__ ushort Xs[3 * 6 * 66 * 8];
    __shared__ ushort Ws[28 * 64 * 8];

    const int tid  = threadIdx.x;
    const int lane = tid & 63;
    const int wave = tid >> 6;
    const int nl   = lane & 15;
    const int quad = lane >> 4;
    const int co_base = wave * 16;

    const int blk = blockIdx.x;
    const int wt  = blk & 15;
    const int h   = (blk >> 4) & 31;
    const int b   = blk >> 9;
    const int w0  = wt * 4;

    float bs[4];
    #pragma unroll
    for (int r = 0; r < 4; ++r) bs[r] = bias[co_base + quad * 4 + r];

    f32x4 acc[16];
    #pragma unroll
    for (int i = 0; i < 16; ++i) acc[i] = (f32x4){0.f, 0.f, 0.f, 0.f};

    for (int cic = 0; cic < 4; ++cic) {
        __syncthreads();
        for (int s = tid; s < 64 * 27; s += 256) {
            int co = s / 27;
            int t  = s - co * 27;
            const float* wp = Wt + ((long)co * C_IN + cic * 8) * 27 + t;
            bf16x8 pk;
            #pragma unroll
            for (int j = 0; j < 8; ++j) pk[j] = (short)f2bf(wp[j * 27]);
            *(bf16x8*)&Ws[(t * 64 + co) * 8] = pk;
        }
        for (int s = tid; s < 64; s += 256) {
            bf16x8 z;
            #pragma unroll
            for (int j = 0; j < 8; ++j) z[j] = 0;
            *(bf16x8*)&Ws[(27 * 64 + s) * 8] = z;
        }
        for (int s = tid; s < 1188; s += 256) {
            int hh   = s / 396;
            int r0   = s - hh * 396;
            int ww   = r0 / 66;
            int dpos = r0 - ww * 66;
            int hp = h - 1 + hh;
            int wp2 = w0 - 1 + ww;
            int dp = dpos - 1;
            bool ok = (unsigned)hp < S_H && (unsigned)wp2 < S_W && (unsigned)dp < S_D;
            int hc = min(max(hp, 0), S_H - 1);
            int wc = min(max(wp2, 0), S_W - 1);
            int dc = min(max(dp, 0), S_D - 1);
            const float* xp = X + (((long)(b * C_IN + cic * 8) * S_H + hc) * S_W + wc) * S_D + dc;
            bf16x8 pk;
            #pragma unroll
            for (int j = 0; j < 8; ++j) {
                float v = xp[(long)j * HWD];
                pk[j] = ok ? (short)f2bf(v) : (short)0;
            }
            *(bf16x8*)&Xs[s * 8] = pk;
        }
        __syncthreads();

        #pragma unroll
        for (int tg = 0; tg < 7; ++tg) {
            int tap = tg * 4 + quad;
            bf16x8 afrag = *(const bf16x8*)&Ws[(tap * 64 + co_base + nl) * 8];
            int tb = tap < 27 ? tap : 0;
            int kh = tb / 9;
            int r9 = tb - kh * 9;
            int kw = r9 / 3;
            int kd = r9 - kw * 3;
            int bbase = ((kh * 6 + kw) * 66 + kd + nl) * 8;
            #pragma unroll
            for (int wi = 0; wi < 4; ++wi) {
                #pragma unroll
                for (int dt = 0; dt < 4; ++dt) {
                    bf16x8 bfrag = *(const bf16x8*)&Xs[bbase + wi * (66 * 8) + dt * (16 * 8)];
                    acc[wi * 4 + dt] = __builtin_amdgcn_mfma_f32_16x16x32_bf16(
                        afrag, bfrag, acc[wi * 4 + dt], 0, 0, 0);
                }
            }
        }
    }

    #pragma unroll
    for (int wi = 0; wi < 4; ++wi) {
        int w = w0 + wi;
        #pragma unroll
        for (int dt = 0; dt < 4; ++dt) {
            int d0 = dt * 16 + nl;
            f32x4 a = acc[wi * 4 + dt];
            #pragma unroll
            for (int r = 0; r < 4; ++r) {
                int co = co_base + quad * 4 + r;
                out[(((long)(b * C_OUT + co) * S_H + h) * S_W + w) * S_D + d0] = a[r] + bs[r];
            }
        }
    }
}

extern "C" void kernel_launch(void* const* d_in, const int* in_sizes, int n_in,
                              void* d_out, int out_size, void* d_ws, size_t ws_size,
                              hipStream_t stream) {
    const float* X    = (const float*)d_in[0];
    const float* Wt   = (const float*)d_in[1];
    const float* bias = (const float*)d_in[2];
    float* out = (float*)d_out;

    if (ws_size >= WS_NEEDED) {
        ushort* Wpk = (ushort*)d_ws;
        float*  Zpf = (float*)((char*)d_ws + (size_t)WPK_USHORTS * 2);
        pack_w_kernel<<<dim3(28),   dim3(256), 0, stream>>>(Wt, Wpk, Zpf);
        conv3d_fused_kernel<<<dim3(2048), dim3(256), 0, stream>>>(X, Wpk, Zpf, bias, out);
    } else {
        conv3d_mfma_fallback<<<dim3(2048), dim3(256), 0, stream>>>(X, Wt, bias, out);
    }
}

// Round 5
// 224.904 us; speedup vs baseline: 1.7027x; 1.7027x over previous
//
#include <hip/hip_runtime.h>
#include <hip/hip_bf16.h>

typedef __attribute__((ext_vector_type(8))) short bf16x8;
typedef __attribute__((ext_vector_type(4))) float f32x4;

#define B_N   4
#define C_IN  32
#define C_OUT 64
#define S_H   32
#define S_W   64
#define S_D   64
#define HWD   (S_H * S_W * S_D)   /* 131072 */

// ws layout: [Wpk 4*28*64*8 ushorts][Zpf 16 floats]
#define WPK_USHORTS     (4 * 28 * 64 * 8)              /* 57344 */
#define WS_NEEDED       ((size_t)WPK_USHORTS * 2 + 64)

__device__ __forceinline__ ushort f2bf(float f) {
    unsigned u = __builtin_bit_cast(unsigned, f);
    unsigned r = (u + 0x7FFFu + ((u >> 16) & 1u)) >> 16;  // RNE
    return (ushort)r;
}

typedef const __attribute__((address_space(1))) unsigned int* dma_gptr;
typedef __attribute__((address_space(3))) unsigned int* dma_lptr;

__device__ __forceinline__ void dma16(const void* g, void* l) {
    __builtin_amdgcn_global_load_lds((dma_gptr)g, (dma_lptr)l, 16, 0, 0);
}

// pinned async global load: issued exactly here, untracked by the legalizer;
// consumer MUST execute an explicit s_waitcnt vmcnt before reading dst.
__device__ __forceinline__ void pin_load(float& dst, const float* p) {
    asm volatile("global_load_dword %0, %1, off" : "=v"(dst) : "v"(p));
}

// ---- prep: pack weights [cic][tap28][co64][ci8] bf16; also zero-page -----
__global__ __launch_bounds__(256) void pack_w_kernel(
    const float* __restrict__ Wt, ushort* __restrict__ Wpk, float* __restrict__ Zpf)
{
    int idx = blockIdx.x * 256 + threadIdx.x;       // 4*28*64 = 7168
    int cic = idx / 1792;
    int r   = idx - cic * 1792;
    int tap = r >> 6;
    int co  = r & 63;
    bf16x8 pk;
    #pragma unroll
    for (int j = 0; j < 8; ++j)
        pk[j] = (tap < 27) ? (short)f2bf(Wt[((long)co * C_IN + cic * 8 + j) * 27 + tap])
                           : (short)0;
    *((bf16x8*)Wpk + idx) = pk;
    if (blockIdx.x == 0 && threadIdx.x < 16) Zpf[threadIdx.x] = 0.f;
}

// ---- main: implicit-GEMM conv3d, fused fp32->bf16 X staging --------------
// Block tile 64co x 256n (4w x 64d). Each wave: 64co x 64n, 4x4 tiles of
// 16x16x32 MFMA. W staged via global_load_lds (L2-resident Wpk).
// X prefetch for cic+1 via PINNED asm global_load_dword issued BEFORE the
// MFMA section; results held in 40 VGPRs across compute; explicit
// s_waitcnt vmcnt(0) + sched_barrier(0) drain after the post-compute
// barrier (asm loads are untracked by the legalizer -- rule #18 vmem).
// R4 LESSON: at __launch_bounds__(256,3) the unified VGPR/AGPR budget is
// ~168/wave; 84 VGPR + 64 acc-AGPR + 40 xv = ~190 -> allocator spilled xv
// to scratch (FETCH 55->278MB, WRITE 131->313MB, 2.5x slower). The pinned
// structure NEEDS the 256-reg budget => __launch_bounds__(256,2). R2 proved
// 3 blocks/CU gains nothing over 2, so the occupancy trade is free.
__global__ __launch_bounds__(256, 2) void conv3d_fused_kernel(
    const float* __restrict__ X, const ushort* __restrict__ Wpk,
    const float* __restrict__ Zpf,
    const float* __restrict__ bias, float* __restrict__ out)
{
    __shared__ ushort Xs[1188 * 8];      // [hh3][ww6][dpos66][ci8]  19008 B
    __shared__ ushort Ws[1792 * 8];      // [tap28][co64][ci8]       28672 B

    const int tid  = threadIdx.x;
    const int lane = tid & 63;
    const int wave = tid >> 6;
    const int nl   = lane & 15;
    const int quad = lane >> 4;

    const int blk = blockIdx.x;       // 2048 blocks = (b4, h32, wt16)
    const int wt  = blk & 15;
    const int h   = (blk >> 4) & 31;
    const int b   = blk >> 9;
    const int w0  = wt * 4;

    // ---- per-site X pointers; pad sites -> zero page with stride 0 --------
    const float* xb[5];
    int adv[5];
    #pragma unroll
    for (int k = 0; k < 5; ++k) {
        int s = tid + k * 256;
        xb[k] = Zpf; adv[k] = 0;
        if (s < 1188) {
            int hh   = s / 396;           // 6*66
            int r0   = s - hh * 396;
            int ww   = r0 / 66;
            int dpos = r0 - ww * 66;
            int hp  = h - 1 + hh;
            int wp2 = w0 - 1 + ww;
            int dp  = dpos - 1;
            bool ok = (unsigned)hp < S_H && (unsigned)wp2 < S_W && (unsigned)dp < S_D;
            if (ok) {
                xb[k]  = X + ((((long)b * C_IN) * S_H + hp) * S_W + wp2) * S_D + dp;
                adv[k] = HWD;
            }
        }
    }

    // ---- per-tg LDS offsets (ushort units) --------------------------------
    int a_off[7], b_off[7];
    #pragma unroll
    for (int tg = 0; tg < 7; ++tg) {
        int tap = tg * 4 + quad;
        int tb  = tap < 27 ? tap : 0;      // pad tap: A rows are zero anyway
        int kh = tb / 9;
        int r9 = tb - kh * 9;
        int kw = r9 / 3;
        int kd = r9 - kw * 3;
        a_off[tg] = (tap * 64 + nl) * 8;
        b_off[tg] = (((kh * 6 + kw + wave) * 66) + kd + nl) * 8;  // ww = wave+kw
    }

    float bs[16];
    #pragma unroll
    for (int mi = 0; mi < 4; ++mi)
        #pragma unroll
        for (int r = 0; r < 4; ++r)
            bs[mi * 4 + r] = bias[mi * 16 + quad * 4 + r];

    f32x4 acc[16];
    #pragma unroll
    for (int i = 0; i < 16; ++i) acc[i] = (f32x4){0.f, 0.f, 0.f, 0.f};

    float xv[5][8];

    // ---- prologue: pinned X loads chunk 0 + W chunk 0 DMA -----------------
    #pragma unroll
    for (int k = 0; k < 5; ++k) {
        int s = tid + k * 256;
        if (s < 1188) {
            #pragma unroll
            for (int j = 0; j < 8; ++j)
                pin_load(xv[k][j], xb[k] + (long)j * adv[k]);
        }
    }
    __builtin_amdgcn_sched_barrier(0);
    #pragma unroll
    for (int k = 0; k < 7; ++k) {
        int s = tid + k * 256;
        dma16(Wpk + s * 8, &Ws[s * 8]);
    }
    __builtin_amdgcn_sched_barrier(0);
    asm volatile("s_waitcnt vmcnt(7)" ::: "memory");   // X drained, W in flight
    __builtin_amdgcn_sched_barrier(0);
    #pragma unroll
    for (int k = 0; k < 5; ++k) {
        int s = tid + k * 256;
        if (s < 1188) {
            bf16x8 pk;
            #pragma unroll
            for (int j = 0; j < 8; ++j) pk[j] = (short)f2bf(xv[k][j]);
            *(bf16x8*)&Xs[s * 8] = pk;
        }
    }

    for (int cic = 0; cic < 4; ++cic) {
        __syncthreads();                 // drains W DMA; Xs[cic] visible

        // pinned async X loads for chunk cic+1 (issued BEFORE compute)
        if (cic < 3) {
            #pragma unroll
            for (int k = 0; k < 5; ++k) {
                int s = tid + k * 256;
                if (s < 1188) {
                    #pragma unroll
                    for (int j = 0; j < 8; ++j)
                        pin_load(xv[k][j],
                                 xb[k] + (long)((cic + 1) * 8 + j) * adv[k]);
                }
            }
        }
        __builtin_amdgcn_sched_barrier(0);   // loads stay above compute

        #pragma unroll
        for (int tg = 0; tg < 7; ++tg) {
            bf16x8 af[4], bf[4];
            #pragma unroll
            for (int mi = 0; mi < 4; ++mi)
                af[mi] = *(const bf16x8*)&Ws[a_off[tg] + mi * 128];   // +mi*16 co
            #pragma unroll
            for (int dt = 0; dt < 4; ++dt)
                bf[dt] = *(const bf16x8*)&Xs[b_off[tg] + dt * 128];   // +dt*16 d
            #pragma unroll
            for (int mi = 0; mi < 4; ++mi)
                #pragma unroll
                for (int dt = 0; dt < 4; ++dt)
                    acc[mi * 4 + dt] = __builtin_amdgcn_mfma_f32_16x16x32_bf16(
                        af[mi], bf[dt], acc[mi * 4 + dt], 0, 0, 0);
        }

        if (cic < 3) {
            __syncthreads();             // compute done; safe to overwrite LDS
            // explicit drain of the pinned X loads (untracked asm loads --
            // never rely on the barrier's implicit waits). They had the whole
            // MFMA section to complete, so this is ~free.
            asm volatile("s_waitcnt vmcnt(0)" ::: "memory");
            __builtin_amdgcn_sched_barrier(0);

            // W chunk cic+1 DMA (drains at next top barrier, behind cvt)
            {
                const ushort* src = Wpk + (long)(cic + 1) * 1792 * 8;
                #pragma unroll
                for (int k = 0; k < 7; ++k) {
                    int s = tid + k * 256;
                    dma16(src + s * 8, &Ws[s * 8]);
                }
            }
            // cvt + write chunk cic+1 (X data already in regs, no wait)
            #pragma unroll
            for (int k = 0; k < 5; ++k) {
                int s = tid + k * 256;
                if (s < 1188) {
                    bf16x8 pk;
                    #pragma unroll
                    for (int j = 0; j < 8; ++j) pk[j] = (short)f2bf(xv[k][j]);
                    *(bf16x8*)&Xs[s * 8] = pk;
                }
            }
        }
    }

    // ---- epilogue: co = mi*16 + quad*4 + r, n = (w0+wave, dt*16+nl) -------
    const int w = w0 + wave;
    #pragma unroll
    for (int mi = 0; mi < 4; ++mi) {
        #pragma unroll
        for (int dt = 0; dt < 4; ++dt) {
            f32x4 a = acc[mi * 4 + dt];
            int d0 = dt * 16 + nl;
            #pragma unroll
            for (int r = 0; r < 4; ++r) {
                int co = mi * 16 + quad * 4 + r;
                out[(((long)(b * C_OUT + co) * S_H + h) * S_W + w) * S_D + d0]
                    = a[r] + bs[mi * 4 + r];
            }
        }
    }
}

// ---- fallback (no workspace needed) ---------------------------------------
__global__ __launch_bounds__(256) void conv3d_mfma_fallback(
    const float* __restrict__ X, const float* __restrict__ Wt,
    const float* __restrict__ bias, float* __restrict__ out)
{
    __shared__ ushort Xs[3 * 6 * 66 * 8];
    __shared__ ushort Ws[28 * 64 * 8];

    const int tid  = threadIdx.x;
    const int lane = tid & 63;
    const int wave = tid >> 6;
    const int nl   = lane & 15;
    const int quad = lane >> 4;
    const int co_base = wave * 16;

    const int blk = blockIdx.x;
    const int wt  = blk & 15;
    const int h   = (blk >> 4) & 31;
    const int b   = blk >> 9;
    const int w0  = wt * 4;

    float bs[4];
    #pragma unroll
    for (int r = 0; r < 4; ++r) bs[r] = bias[co_base + quad * 4 + r];

    f32x4 acc[16];
    #pragma unroll
    for (int i = 0; i < 16; ++i) acc[i] = (f32x4){0.f, 0.f, 0.f, 0.f};

    for (int cic = 0; cic < 4; ++cic) {
        __syncthreads();
        for (int s = tid; s < 64 * 27; s += 256) {
            int co = s / 27;
            int t  = s - co * 27;
            const float* wp = Wt + ((long)co * C_IN + cic * 8) * 27 + t;
            bf16x8 pk;
            #pragma unroll
            for (int j = 0; j < 8; ++j) pk[j] = (short)f2bf(wp[j * 27]);
            *(bf16x8*)&Ws[(t * 64 + co) * 8] = pk;
        }
        for (int s = tid; s < 64; s += 256) {
            bf16x8 z;
            #pragma unroll
            for (int j = 0; j < 8; ++j) z[j] = 0;
            *(bf16x8*)&Ws[(27 * 64 + s) * 8] = z;
        }
        for (int s = tid; s < 1188; s += 256) {
            int hh   = s / 396;
            int r0   = s - hh * 396;
            int ww   = r0 / 66;
            int dpos = r0 - ww * 66;
            int hp = h - 1 + hh;
            int wp2 = w0 - 1 + ww;
            int dp = dpos - 1;
            bool ok = (unsigned)hp < S_H && (unsigned)wp2 < S_W && (unsigned)dp < S_D;
            int hc = min(max(hp, 0), S_H - 1);
            int wc = min(max(wp2, 0), S_W - 1);
            int dc = min(max(dp, 0), S_D - 1);
            const float* xp = X + (((long)(b * C_IN + cic * 8) * S_H + hc) * S_W + wc) * S_D + dc;
            bf16x8 pk;
            #pragma unroll
            for (int j = 0; j < 8; ++j) {
                float v = xp[(long)j * HWD];
                pk[j] = ok ? (short)f2bf(v) : (short)0;
            }
            *(bf16x8*)&Xs[s * 8] = pk;
        }
        __syncthreads();

        #pragma unroll
        for (int tg = 0; tg < 7; ++tg) {
            int tap = tg * 4 + quad;
            bf16x8 afrag = *(const bf16x8*)&Ws[(tap * 64 + co_base + nl) * 8];
            int tb = tap < 27 ? tap : 0;
            int kh = tb / 9;
            int r9 = tb - kh * 9;
            int kw = r9 / 3;
            int kd = r9 - kw * 3;
            int bbase = ((kh * 6 + kw) * 66 + kd + nl) * 8;
            #pragma unroll
            for (int wi = 0; wi < 4; ++wi) {
                #pragma unroll
                for (int dt = 0; dt < 4; ++dt) {
                    bf16x8 bfrag = *(const bf16x8*)&Xs[bbase + wi * (66 * 8) + dt * (16 * 8)];
                    acc[wi * 4 + dt] = __builtin_amdgcn_mfma_f32_16x16x32_bf16(
                        afrag, bfrag, acc[wi * 4 + dt], 0, 0, 0);
                }
            }
        }
    }

    #pragma unroll
    for (int wi = 0; wi < 4; ++wi) {
        int w = w0 + wi;
        #pragma unroll
        for (int dt = 0; dt < 4; ++dt) {
            int d0 = dt * 16 + nl;
            f32x4 a = acc[wi * 4 + dt];
            #pragma unroll
            for (int r = 0; r < 4; ++r) {
                int co = co_base + quad * 4 + r;
                out[(((long)(b * C_OUT + co) * S_H + h) * S_W + w) * S_D + d0] = a[r] + bs[r];
            }
        }
    }
}

extern "C" void kernel_launch(void* const* d_in, const int* in_sizes, int n_in,
                              void* d_out, int out_size, void* d_ws, size_t ws_size,
                              hipStream_t stream) {
    const float* X    = (const float*)d_in[0];
    const float* Wt   = (const float*)d_in[1];
    const float* bias = (const float*)d_in[2];
    float* out = (float*)d_out;

    if (ws_size >= WS_NEEDED) {
        ushort* Wpk = (ushort*)d_ws;
        float*  Zpf = (float*)((char*)d_ws + (size_t)WPK_USHORTS * 2);
        pack_w_kernel<<<dim3(28),   dim3(256), 0, stream>>>(Wt, Wpk, Zpf);
        conv3d_fused_kernel<<<dim3(2048), dim3(256), 0, stream>>>(X, Wpk, Zpf, bias, out);
    } else {
        conv3d_mfma_fallback<<<dim3(2048), dim3(256), 0, stream>>>(X, Wt, bias, out);
    }
}

// Round 6
// 216.048 us; speedup vs baseline: 1.7725x; 1.0410x over previous
//
#include <hip/hip_runtime.h>
#include <hip/hip_bf16.h>

typedef __attribute__((ext_vector_type(8))) short bf16x8;
typedef __attribute__((ext_vector_type(4))) float f32x4;

#define B_N   4
#define C_IN  32
#define C_OUT 64
#define S_H   32
#define S_W   64
#define S_D   64
#define HWD   (S_H * S_W * S_D)   /* 131072 */

// ws layout: [Wpk 4*28*64*8 ushorts][Zpf 16 floats]
#define WPK_USHORTS     (4 * 28 * 64 * 8)              /* 57344 */
#define WS_NEEDED       ((size_t)WPK_USHORTS * 2 + 64)

__device__ __forceinline__ ushort f2bf(float f) {
    unsigned u = __builtin_bit_cast(unsigned, f);
    unsigned r = (u + 0x7FFFu + ((u >> 16) & 1u)) >> 16;  // RNE
    return (ushort)r;
}

typedef const __attribute__((address_space(1))) unsigned int* dma_gptr;
typedef __attribute__((address_space(3))) unsigned int* dma_lptr;

__device__ __forceinline__ void dma16(const void* g, void* l) {
    __builtin_amdgcn_global_load_lds((dma_gptr)g, (dma_lptr)l, 16, 0, 0);
}

// ---- prep: pack weights [cic][tap28][co64][ci8] bf16; also zero-page -----
__global__ __launch_bounds__(256) void pack_w_kernel(
    const float* __restrict__ Wt, ushort* __restrict__ Wpk, float* __restrict__ Zpf)
{
    int idx = blockIdx.x * 256 + threadIdx.x;       // 4*28*64 = 7168
    int cic = idx / 1792;
    int r   = idx - cic * 1792;
    int tap = r >> 6;
    int co  = r & 63;
    bf16x8 pk;
    #pragma unroll
    for (int j = 0; j < 8; ++j)
        pk[j] = (tap < 27) ? (short)f2bf(Wt[((long)co * C_IN + cic * 8 + j) * 27 + tap])
                           : (short)0;
    *((bf16x8*)Wpk + idx) = pk;
    if (blockIdx.x == 0 && threadIdx.x < 16) Zpf[threadIdx.x] = 0.f;
}

// ---- main: implicit-GEMM conv3d, fused fp32->bf16 X staging --------------
// R6: block tile widened to 64co x 8w x 64d (grid 1024, 4 waves, each wave
// owns TWO w columns). Rationale: R1/R2/R5 varied staging schedule and
// occupancy (2 vs 3 blk/CU) and ALL landed at 94-97us, MfmaUtil~25% -- the
// invariants were (a) 0.5 ds_read_b128 per MFMA and (b) only 112 MFMAs per
// barrier interval. Now per tg: 4 A + 8 B reads feed 32 MFMAs (0.375
// reads/MFMA, -25% LDS traffic) and 224 MFMAs/barrier-interval (2x chain).
// LDS 60.4KB -> 2 blocks/CU. acc = 32 f32x4 = 128 regs; staging in two
// 4-slot groups bounds pressure (~230 regs, fits the (256,2) budget; R4
// showed spill signature = FETCH/WRITE explosion -- check post-mortem).
// Numerics identical to R5 (same tap/cic accumulation order).
__global__ __launch_bounds__(256, 2) void conv3d_fused_kernel(
    const float* __restrict__ X, const ushort* __restrict__ Wpk,
    const float* __restrict__ Zpf,
    const float* __restrict__ bias, float* __restrict__ out)
{
    __shared__ ushort Xs[1980 * 8];      // [hh3][ww10][dpos66][ci8] 31680 B
    __shared__ ushort Ws[1792 * 8];      // [tap28][co64][ci8]       28672 B

    const int tid  = threadIdx.x;
    const int lane = tid & 63;
    const int wave = tid >> 6;           // 0..3
    const int nl   = lane & 15;
    const int quad = lane >> 4;

    const int blk = blockIdx.x;          // 1024 blocks = (b4, h32, wt8)
    const int wt  = blk & 7;
    const int h   = (blk >> 3) & 31;
    const int b   = blk >> 8;
    const int w0  = wt * 8;

    // ---- per-site X pointers (8 slots); pad sites -> zero page, stride 0 --
    const float* xb[8];
    int adv[8];
    #pragma unroll
    for (int k = 0; k < 8; ++k) {
        int s = tid + k * 256;
        xb[k] = Zpf; adv[k] = 0;
        if (s < 1980) {
            int hh   = s / 660;           // 10*66
            int r0   = s - hh * 660;
            int ww   = r0 / 66;
            int dpos = r0 - ww * 66;
            int hp  = h - 1 + hh;
            int wp2 = w0 - 1 + ww;
            int dp  = dpos - 1;
            bool ok = (unsigned)hp < S_H && (unsigned)wp2 < S_W && (unsigned)dp < S_D;
            if (ok) {
                xb[k]  = X + ((((long)b * C_IN) * S_H + hp) * S_W + wp2) * S_D + dp;
                adv[k] = HWD;
            }
        }
    }

    // ---- per-tg LDS offsets (ushort units) --------------------------------
    int a_off[7], b_off[7];
    #pragma unroll
    for (int tg = 0; tg < 7; ++tg) {
        int tap = tg * 4 + quad;
        int tb  = tap < 27 ? tap : 0;      // pad tap: A rows are zero anyway
        int kh = tb / 9;
        int r9 = tb - kh * 9;
        int kw = r9 / 3;
        int kd = r9 - kw * 3;
        a_off[tg] = (tap * 64 + nl) * 8;
        // ww = wave*2 + wo + kw; wo=0 here, wo=1 adds 66*8 ushorts
        b_off[tg] = (((kh * 10 + wave * 2 + kw) * 66) + kd + nl) * 8;
    }

    float bs[16];
    #pragma unroll
    for (int mi = 0; mi < 4; ++mi)
        #pragma unroll
        for (int r = 0; r < 4; ++r)
            bs[mi * 4 + r] = bias[mi * 16 + quad * 4 + r];

    f32x4 acc[32];                       // [wo2][mi4][dt4]
    #pragma unroll
    for (int i = 0; i < 32; ++i) acc[i] = (f32x4){0.f, 0.f, 0.f, 0.f};

    // ---- staging macro-equivalent: two 4-slot groups (bounds reg pressure)
    // group g: slots g*4..g*4+3; loads 32 floats -> cvt -> 4 ds_write_b128.
    #define STAGE_X(cc)                                                       \
        do {                                                                  \
            _Pragma("unroll")                                                 \
            for (int g = 0; g < 2; ++g) {                                     \
                float xv[4][8];                                               \
                _Pragma("unroll")                                             \
                for (int k = 0; k < 4; ++k) {                                 \
                    int kk = g * 4 + k;                                       \
                    int s  = tid + kk * 256;                                  \
                    if (s < 1980) {                                           \
                        _Pragma("unroll")                                     \
                        for (int j = 0; j < 8; ++j)                           \
                            xv[k][j] = xb[kk][(long)((cc) * 8 + j) * adv[kk]];\
                    }                                                         \
                }                                                             \
                _Pragma("unroll")                                             \
                for (int k = 0; k < 4; ++k) {                                 \
                    int kk = g * 4 + k;                                       \
                    int s  = tid + kk * 256;                                  \
                    if (s < 1980) {                                           \
                        bf16x8 pk;                                            \
                        _Pragma("unroll")                                     \
                        for (int j = 0; j < 8; ++j)                           \
                            pk[j] = (short)f2bf(xv[k][j]);                    \
                        *(bf16x8*)&Xs[s * 8] = pk;                            \
                    }                                                         \
                }                                                             \
            }                                                                 \
        } while (0)

    // ---- prologue: W chunk 0 DMA + X chunk 0 stage ------------------------
    #pragma unroll
    for (int k = 0; k < 7; ++k) {
        int s = tid + k * 256;
        dma16(Wpk + s * 8, &Ws[s * 8]);
    }
    STAGE_X(0);

    for (int cic = 0; cic < 4; ++cic) {
        __syncthreads();                 // drains W DMA (vmcnt) + Xs writes

        #pragma unroll
        for (int tg = 0; tg < 7; ++tg) {
            bf16x8 af[4];
            #pragma unroll
            for (int mi = 0; mi < 4; ++mi)
                af[mi] = *(const bf16x8*)&Ws[a_off[tg] + mi * 128];   // +mi*16 co
            #pragma unroll
            for (int wo = 0; wo < 2; ++wo) {
                bf16x8 bf[4];
                #pragma unroll
                for (int dt = 0; dt < 4; ++dt)
                    bf[dt] = *(const bf16x8*)&Xs[b_off[tg] + wo * 528 + dt * 128];
                #pragma unroll
                for (int mi = 0; mi < 4; ++mi)
                    #pragma unroll
                    for (int dt = 0; dt < 4; ++dt)
                        acc[wo * 16 + mi * 4 + dt] =
                            __builtin_amdgcn_mfma_f32_16x16x32_bf16(
                                af[mi], bf[dt], acc[wo * 16 + mi * 4 + dt], 0, 0, 0);
            }
        }

        if (cic < 3) {
            __syncthreads();             // compute done; safe to overwrite LDS

            // W chunk cic+1 DMA (drains at next top barrier, behind staging)
            {
                const ushort* src = Wpk + (long)(cic + 1) * 1792 * 8;
                #pragma unroll
                for (int k = 0; k < 7; ++k) {
                    int s = tid + k * 256;
                    dma16(src + s * 8, &Ws[s * 8]);
                }
            }
            STAGE_X(cic + 1);
        }
    }
    #undef STAGE_X

    // ---- epilogue: co = mi*16 + quad*4 + r; w = w0 + wave*2 + wo ----------
    #pragma unroll
    for (int wo = 0; wo < 2; ++wo) {
        const int w = w0 + wave * 2 + wo;
        #pragma unroll
        for (int mi = 0; mi < 4; ++mi) {
            #pragma unroll
            for (int dt = 0; dt < 4; ++dt) {
                f32x4 a = acc[wo * 16 + mi * 4 + dt];
                int d0 = dt * 16 + nl;
                #pragma unroll
                for (int r = 0; r < 4; ++r) {
                    int co = mi * 16 + quad * 4 + r;
                    out[(((long)(b * C_OUT + co) * S_H + h) * S_W + w) * S_D + d0]
                        = a[r] + bs[mi * 4 + r];
                }
            }
        }
    }
}

// ---- fallback (no workspace needed) ---------------------------------------
__global__ __launch_bounds__(256) void conv3d_mfma_fallback(
    const float* __restrict__ X, const float* __restrict__ Wt,
    const float* __restrict__ bias, float* __restrict__ out)
{
    __shared__ ushort Xs[3 * 6 * 66 * 8];
    __shared__ ushort Ws[28 * 64 * 8];

    const int tid  = threadIdx.x;
    const int lane = tid & 63;
    const int wave = tid >> 6;
    const int nl   = lane & 15;
    const int quad = lane >> 4;
    const int co_base = wave * 16;

    const int blk = blockIdx.x;
    const int wt  = blk & 15;
    const int h   = (blk >> 4) & 31;
    const int b   = blk >> 9;
    const int w0  = wt * 4;

    float bs[4];
    #pragma unroll
    for (int r = 0; r < 4; ++r) bs[r] = bias[co_base + quad * 4 + r];

    f32x4 acc[16];
    #pragma unroll
    for (int i = 0; i < 16; ++i) acc[i] = (f32x4){0.f, 0.f, 0.f, 0.f};

    for (int cic = 0; cic < 4; ++cic) {
        __syncthreads();
        for (int s = tid; s < 64 * 27; s += 256) {
            int co = s / 27;
            int t  = s - co * 27;
            const float* wp = Wt + ((long)co * C_IN + cic * 8) * 27 + t;
            bf16x8 pk;
            #pragma unroll
            for (int j = 0; j < 8; ++j) pk[j] = (short)f2bf(wp[j * 27]);
            *(bf16x8*)&Ws[(t * 64 + co) * 8] = pk;
        }
        for (int s = tid; s < 64; s += 256) {
            bf16x8 z;
            #pragma unroll
            for (int j = 0; j < 8; ++j) z[j] = 0;
            *(bf16x8*)&Ws[(27 * 64 + s) * 8] = z;
        }
        for (int s = tid; s < 1188; s += 256) {
            int hh   = s / 396;
            int r0   = s - hh * 396;
            int ww   = r0 / 66;
            int dpos = r0 - ww * 66;
            int hp = h - 1 + hh;
            int wp2 = w0 - 1 + ww;
            int dp = dpos - 1;
            bool ok = (unsigned)hp < S_H && (unsigned)wp2 < S_W && (unsigned)dp < S_D;
            int hc = min(max(hp, 0), S_H - 1);
            int wc = min(max(wp2, 0), S_W - 1);
            int dc = min(max(dp, 0), S_D - 1);
            const float* xp = X + (((long)(b * C_IN + cic * 8) * S_H + hc) * S_W + wc) * S_D + dc;
            bf16x8 pk;
            #pragma unroll
            for (int j = 0; j < 8; ++j) {
                float v = xp[(long)j * HWD];
                pk[j] = ok ? (short)f2bf(v) : (short)0;
            }
            *(bf16x8*)&Xs[s * 8] = pk;
        }
        __syncthreads();

        #pragma unroll
        for (int tg = 0; tg < 7; ++tg) {
            int tap = tg * 4 + quad;
            bf16x8 afrag = *(const bf16x8*)&Ws[(tap * 64 + co_base + nl) * 8];
            int tb = tap < 27 ? tap : 0;
            int kh = tb / 9;
            int r9 = tb - kh * 9;
            int kw = r9 / 3;
            int kd = r9 - kw * 3;
            int bbase = ((kh * 6 + kw) * 66 + kd + nl) * 8;
            #pragma unroll
            for (int wi = 0; wi < 4; ++wi) {
                #pragma unroll
                for (int dt = 0; dt < 4; ++dt) {
                    bf16x8 bfrag = *(const bf16x8*)&Xs[bbase + wi * (66 * 8) + dt * (16 * 8)];
                    acc[wi * 4 + dt] = __builtin_amdgcn_mfma_f32_16x16x32_bf16(
                        afrag, bfrag, acc[wi * 4 + dt], 0, 0, 0);
                }
            }
        }
    }

    #pragma unroll
    for (int wi = 0; wi < 4; ++wi) {
        int w = w0 + wi;
        #pragma unroll
        for (int dt = 0; dt < 4; ++dt) {
            int d0 = dt * 16 + nl;
            f32x4 a = acc[wi * 4 + dt];
            #pragma unroll
            for (int r = 0; r < 4; ++r) {
                int co = co_base + quad * 4 + r;
                out[(((long)(b * C_OUT + co) * S_H + h) * S_W + w) * S_D + d0] = a[r] + bs[r];
            }
        }
    }
}

extern "C" void kernel_launch(void* const* d_in, const int* in_sizes, int n_in,
                              void* d_out, int out_size, void* d_ws, size_t ws_size,
                              hipStream_t stream) {
    const float* X    = (const float*)d_in[0];
    const float* Wt   = (const float*)d_in[1];
    const float* bias = (const float*)d_in[2];
    float* out = (float*)d_out;

    if (ws_size >= WS_NEEDED) {
        ushort* Wpk = (ushort*)d_ws;
        float*  Zpf = (float*)((char*)d_ws + (size_t)WPK_USHORTS * 2);
        pack_w_kernel<<<dim3(28),   dim3(256), 0, stream>>>(Wt, Wpk, Zpf);
        conv3d_fused_kernel<<<dim3(1024), dim3(256), 0, stream>>>(X, Wpk, Zpf, bias, out);
    } else {
        conv3d_mfma_fallback<<<dim3(2048), dim3(256), 0, stream>>>(X, Wt, bias, out);
    }
}